// Round 10
// baseline (413.572 us; speedup 1.0000x reference)
//
#include <hip/hip_runtime.h>

constexpr int NTYPES = 8;
constexpr int NREL   = 6;
constexpr int NSLOT  = 7;          // 6 relations + self
constexpr int D      = 256;
constexpr int DIN    = 512;
constexpr int LDH    = NSLOT * D;  // 1792

using short8 = __attribute__((ext_vector_type(8))) short;
using f32x4  = __attribute__((ext_vector_type(4))) float;

__device__ __forceinline__ ushort f2b(float f) {  // f32 -> bf16 RNE
  unsigned u = __float_as_uint(f);
  u += 0x7fffu + ((u >> 16) & 1u);
  return (ushort)(u >> 16);
}
__device__ __forceinline__ float b2f(unsigned bits16) {
  return __uint_as_float(bits16 << 16);
}

#define GLOAD_LDS16(g, l)                                              \
  __builtin_amdgcn_global_load_lds(                                    \
      (__attribute__((address_space(1))) void*)(g),                    \
      (__attribute__((address_space(3))) void*)(l), 16, 0, 0)

// ---------------- prep kernels ----------------
__global__ void k_zero(int* __restrict__ p, int n) {
  int i = blockIdx.x * blockDim.x + threadIdx.x;
  if (i < n) p[i] = 0;
}

__global__ void k_cvt_bf16(const float* __restrict__ in, ushort* __restrict__ out, int n4) {
  int i = blockIdx.x * blockDim.x + threadIdx.x;
  if (i >= n4) return;
  float4 v = ((const float4*)in)[i];
  ushort4 o;
  o.x = f2b(v.x); o.y = f2b(v.y); o.z = f2b(v.z); o.w = f2b(v.w);
  ((ushort4*)out)[i] = o;
}

// W2[l][e][k] : k<1536 -> W_rel[l][k/256][k%256][e] ; k>=1536 -> W_self[l][k-1536][e]
// (aggregate-first layout: out[n][e] = sum_k A[n][k] * W2[e][k], A = [S | h])
__global__ void k_pack_wcat2(const float* __restrict__ Wrel, const float* __restrict__ Wself,
                             ushort* __restrict__ W2) {
  int l = blockIdx.y;
  int idx = blockIdx.x * 256 + threadIdx.x;   // over D*LDH
  int e = idx / LDH, k = idx % LDH;
  float v = (k < NREL * D)
                ? Wrel[(((size_t)l * NREL + (k >> 8)) * D + (k & 255)) * D + e]
                : Wself[((size_t)l * D + (k - NREL * D)) * D + e];
  W2[((size_t)l * D + e) * LDH + k] = f2b(v);
}

// ---- contention-free counting sort by node type (ballot-based, 3 phases) ----
__global__ void k_type_blockcnt(const int* __restrict__ ntype, int* __restrict__ blockcnt,
                                int N) {
  __shared__ int cnt[NTYPES];
  int i = blockIdx.x * 256 + threadIdx.x;
  if (threadIdx.x < NTYPES) cnt[threadIdx.x] = 0;
  __syncthreads();
  int t = (i < N) ? ntype[i] : -1;
#pragma unroll
  for (int ty = 0; ty < NTYPES; ++ty) {
    unsigned long long m = __ballot(t == ty);
    if ((threadIdx.x & 63) == 0 && m) atomicAdd(&cnt[ty], __popcll(m));
  }
  __syncthreads();
  if (threadIdx.x < NTYPES) blockcnt[blockIdx.x * NTYPES + threadIdx.x] = cnt[threadIdx.x];
}

__global__ void k_type_scan(const int* __restrict__ blockcnt, int* __restrict__ boffset,
                            int* __restrict__ cnt, int* __restrict__ offt, int nb) {
  __shared__ int tot[NTYPES];
  __shared__ int base[NTYPES];
  int t = threadIdx.x;
  if (t < NTYPES) {
    int s = 0;
    for (int b = 0; b < nb; ++b) {
      boffset[b * NTYPES + t] = s;
      s += blockcnt[b * NTYPES + t];
    }
    tot[t] = s;
    cnt[t] = s;
  }
  __syncthreads();
  if (t == 0) {
    int s = 0;
    for (int ty = 0; ty < NTYPES; ++ty) { base[ty] = s; offt[ty] = s; s += tot[ty]; }
  }
  __syncthreads();
  if (t < NTYPES)
    for (int b = 0; b < nb; ++b) boffset[b * NTYPES + t] += base[t];
}

__global__ void k_type_scatter(const int* __restrict__ ntype, const int* __restrict__ boffset,
                               int* __restrict__ perm, int N) {
  __shared__ int cur[NTYPES];
  int i = blockIdx.x * 256 + threadIdx.x;
  if (threadIdx.x < NTYPES) cur[threadIdx.x] = boffset[blockIdx.x * NTYPES + threadIdx.x];
  __syncthreads();
  int t = (i < N) ? ntype[i] : -1;
  int lane = threadIdx.x & 63;
#pragma unroll
  for (int ty = 0; ty < NTYPES; ++ty) {
    unsigned long long m = __ballot(t == ty);
    if (m) {
      int wbase = 0;
      if (lane == 0) wbase = atomicAdd(&cur[ty], __popcll(m));
      wbase = __shfl(wbase, 0);
      if (t == ty) {
        int rank = __popcll(m & ((1ull << lane) - 1ull));
        perm[wbase + rank] = i;
      }
    }
  }
}

__global__ void k_degree(const int* __restrict__ dst, int* deg, int E) {
  int i = blockIdx.x * blockDim.x + threadIdx.x;
  if (i < E) atomicAdd(&deg[dst[i]], 1);
}

// ---------------- CSR build (3-phase scan + counting sort) ----------------
__global__ void k_scan_block(const int* __restrict__ deg, int* __restrict__ rowptr,
                             int* __restrict__ bsum, int N) {
  __shared__ int s[256];
  int i = blockIdx.x * 256 + threadIdx.x;
  int v = (i < N) ? deg[i] : 0;
  s[threadIdx.x] = v;
  __syncthreads();
  for (int o = 1; o < 256; o <<= 1) {
    int t = (threadIdx.x >= o) ? s[threadIdx.x - o] : 0;
    __syncthreads();
    s[threadIdx.x] += t;
    __syncthreads();
  }
  if (i < N) rowptr[i] = s[threadIdx.x] - v;   // exclusive within block
  if (threadIdx.x == 255) bsum[blockIdx.x] = s[255];
}
__global__ void k_scan_bsum(int* bsum, int nb) {
  if (threadIdx.x == 0) {
    int s = 0;
    for (int b = 0; b < nb; ++b) { int t = bsum[b]; bsum[b] = s; s += t; }
  }
}
// adds block offsets AND computes inv_deg in the same pass
__global__ void k_scan_add(int* __restrict__ rowptr, int* __restrict__ cursor,
                           const int* __restrict__ bsum, const int* __restrict__ deg,
                           float* __restrict__ inv, int N, int E) {
  int i = blockIdx.x * 256 + threadIdx.x;
  if (i < N) {
    int r = rowptr[i] + bsum[blockIdx.x];
    rowptr[i] = r;
    cursor[i] = r;
    inv[i] = 1.0f / fmaxf((float)deg[i], 1.0f);
  }
  if (i == 0) rowptr[N] = E;
}
__global__ void k_sortedges(const int* __restrict__ src, const int* __restrict__ dst,
                            const int* __restrict__ et, int* cursor,
                            int* __restrict__ epack, int E) {
  int e = blockIdx.x * 256 + threadIdx.x;
  if (e < E) {
    int pos = atomicAdd(&cursor[dst[e]], 1);
    epack[pos] = (src[e] << 3) | et[e];
  }
}

// ---------------- per-node aggregate (aggregate-first reorder) ----------------
// S[v] = [ inv[v]*Σ_{e∈in_0(v)} h[src_e] | ... rel 5 ... | h[v] ]   (bf16, [N,1792])
// one wave per node, lane owns 4 channels; 8 gathers in flight; relation index
// made wave-uniform via readfirstlane so the switch is scalar branches and the
// f32 accumulators stay register-resident (rule #20).
__global__ void k_aggregate(const ushort* __restrict__ h, const int* __restrict__ rowptr,
                            const int* __restrict__ epack, const float* __restrict__ invd,
                            ushort* __restrict__ S, int N) {
  int v = blockIdx.x * 4 + (threadIdx.x >> 6);
  if (v >= N) return;
  int lane = threadIdx.x & 63;
  float acc[NREL][4] = {};
  int e0 = rowptr[v], e1 = rowptr[v + 1];

  auto ACC = [&](int p, uint2 u) {
    float f0 = b2f(u.x & 0xffffu), f1 = __uint_as_float(u.x & 0xffff0000u);
    float f2 = b2f(u.y & 0xffffu), f3 = __uint_as_float(u.y & 0xffff0000u);
    int r = __builtin_amdgcn_readfirstlane(p) & 7;   // wave-uniform scalar
    switch (r) {
      case 0: acc[0][0]+=f0; acc[0][1]+=f1; acc[0][2]+=f2; acc[0][3]+=f3; break;
      case 1: acc[1][0]+=f0; acc[1][1]+=f1; acc[1][2]+=f2; acc[1][3]+=f3; break;
      case 2: acc[2][0]+=f0; acc[2][1]+=f1; acc[2][2]+=f2; acc[2][3]+=f3; break;
      case 3: acc[3][0]+=f0; acc[3][1]+=f1; acc[3][2]+=f2; acc[3][3]+=f3; break;
      case 4: acc[4][0]+=f0; acc[4][1]+=f1; acc[4][2]+=f2; acc[4][3]+=f3; break;
      default: acc[5][0]+=f0; acc[5][1]+=f1; acc[5][2]+=f2; acc[5][3]+=f3; break;
    }
  };

  int e = e0;
  for (; e + 8 <= e1; e += 8) {
    int p[8]; uint2 u[8];
#pragma unroll
    for (int k = 0; k < 8; ++k) {
      p[k] = epack[e + k];
      u[k] = *(const uint2*)(h + (size_t)(p[k] >> 3) * D + lane * 4);
    }
#pragma unroll
    for (int k = 0; k < 8; ++k) ACC(p[k], u[k]);
  }
  for (; e < e1; ++e) {
    int p = epack[e];
    uint2 u = *(const uint2*)(h + (size_t)(p >> 3) * D + lane * 4);
    ACC(p, u);
  }

  float iv = invd[v];
#pragma unroll
  for (int r = 0; r < NREL; ++r) {
    ushort4 o;
    o.x = f2b(acc[r][0] * iv); o.y = f2b(acc[r][1] * iv);
    o.z = f2b(acc[r][2] * iv); o.w = f2b(acc[r][3] * iv);
    *(ushort4*)(S + (size_t)v * LDH + r * D + lane * 4) = o;
  }
  // self slot: copy h[v] (already bf16)
  uint2 sh = *(const uint2*)(h + (size_t)v * D + lane * 4);
  *(uint2*)(S + (size_t)v * LDH + NREL * D + lane * 4) = sh;
}

// ---------------- MFMA GEMM (1D swizzled grid) ----------------
// C[m][n] = sum_k A[m][k] * B[n][k]   (B row-per-output-col, k-contiguous)
// BMxBN tile, 4 waves (2x2), BK=32, bf16 in / f32 acc.
// EPI: 0 = tanh+bias -> bf16 (adapt, perm-gathered rows)
//      1 = relu+bias -> bf16 (layer 0)
//      2 = relu+bias -> f32 direct store (layer 1 -> d_out)
// K-loop: paired double-buffer bodies with REAL __syncthreads() (rounds 6-7
// lesson: raw s_barrier is IntrNoMem and lets STAGE hoist across it).
template <int BM, int BN, int NTN, int KDIM, bool ADAPT, int EPI, int OCC>
__global__ __launch_bounds__(256, OCC)
void k_mfma_gemm(const ushort* __restrict__ A, const ushort* __restrict__ B,
                 const float* __restrict__ bias,
                 const int* __restrict__ perm, const int* __restrict__ cnt,
                 const int* __restrict__ off,
                 void* __restrict__ Cout, int N, int ldC) {
  // bijective XCD swizzle (works for any nwg)
  const int nwg = gridDim.x;
  const int qq = nwg >> 3, rr = nwg & 7;
  const int xcd = blockIdx.x & 7, idx = blockIdx.x >> 3;
  const int wgid = (xcd < rr ? xcd * (qq + 1) : rr * (qq + 1) + (xcd - rr) * qq) + idx;

  int mcnt = N, mtile, ntile;
  const int* permt = nullptr;
  const ushort* Bt = B;
  const float* biast = bias;
  if (ADAPT) {
    const int mt = nwg / (NTYPES * NTN);
    const int t = wgid / (mt * NTN);
    const int rem = wgid % (mt * NTN);
    mtile = rem / NTN;
    ntile = rem % NTN;
    mcnt = cnt[t];
    permt = perm + off[t];
    Bt = B + (size_t)t * D * KDIM;
    biast = bias + t * D;
  } else {
    mtile = wgid / NTN;
    ntile = wgid % NTN;
  }
  const int m0 = mtile * BM;
  if (m0 >= mcnt) return;
  const int n0 = ntile * BN;

  __shared__ ushort SM[2][2][BM * 32];   // [buf][A=0/B=1][row*32+k]
  static_assert(EPI == 2 || BM * BN <= 2 * 2 * BM * 32, "C tile must fit staging LDS");

  const int tid  = threadIdx.x;
  const int lane = tid & 63;
  const int w    = tid >> 6;
  constexpr int FR = BM / 32;
  constexpr int FC = BN / 32;
  const int wr   = (w >> 1) * (BM / 2);
  const int wc   = (w & 1) * (BN / 2);

  // staging: (BM/16) x 1KB calls per matrix; wave w does calls {w, w+4, ...}.
  // XOR swizzle on GLOBAL source slot (LDS dest linear), undone at ds_read.
  constexpr int PW = BM / 16 / 4;
  const ushort* gA[PW];
  const ushort* gB[PW];
  int lo[PW];
#pragma unroll
  for (int u = 0; u < PW; ++u) {
    const int c  = w + u * 4;
    const int r  = c * 16 + (lane >> 2);
    const int sl = (lane & 3) ^ ((r >> 1) & 3);
    int ga;
    if (ADAPT) ga = permt[min(m0 + r, mcnt - 1)];
    else       ga = min(m0 + r, N - 1);
    gA[u] = A + (size_t)ga * KDIM + sl * 8;
    gB[u] = Bt + (size_t)(n0 + r) * KDIM + sl * 8;
    lo[u] = c * 512;
  }

  auto STAGE = [&](int k0, int buf) {
#pragma unroll
    for (int u = 0; u < PW; ++u) {
      GLOAD_LDS16(gA[u] + k0, &SM[buf][0][lo[u]]);
      GLOAD_LDS16(gB[u] + k0, &SM[buf][1][lo[u]]);
    }
  };

  f32x4 acc[FR][FC] = {};
  const int r15 = lane & 15;
  const int g   = lane >> 4;
  const int gsw = g ^ ((r15 >> 1) & 3);

  constexpr int NT = KDIM / 32;
  static_assert((NT & 1) == 0, "paired double-buffer needs even NT");

  auto KSTEP = [&](int kt, int buf) {
    if (kt + 1 < NT) STAGE((kt + 1) * 32, buf ^ 1);
    short8 af[FR], bf[FC];
#pragma unroll
    for (int i = 0; i < FR; ++i)
      af[i] = *(const short8*)(&SM[buf][0][(wr + i * 16 + r15) * 32 + gsw * 8]);
#pragma unroll
    for (int j = 0; j < FC; ++j)
      bf[j] = *(const short8*)(&SM[buf][1][(wc + j * 16 + r15) * 32 + gsw * 8]);
#pragma unroll
    for (int i = 0; i < FR; ++i)
#pragma unroll
      for (int j = 0; j < FC; ++j)
        acc[i][j] = __builtin_amdgcn_mfma_f32_16x16x32_bf16(af[i], bf[j], acc[i][j], 0, 0, 0);
    __syncthreads();   // real fence+barrier: prefetch landed, reads joined
  };

  STAGE(0, 0);
  __syncthreads();
  for (int kt2 = 0; kt2 < NT / 2; ++kt2) {
    KSTEP(2 * kt2, 0);
    KSTEP(2 * kt2 + 1, 1);
  }

  // ---- epilogue: C/D layout (m89): col = lane&15, row = (lane>>4)*4 + reg ----
  if constexpr (EPI == 2) {
    float* Co = (float*)Cout;
#pragma unroll
    for (int i = 0; i < FR; ++i) {
#pragma unroll
      for (int q4 = 0; q4 < 4; ++q4) {
        const int m = m0 + wr + i * 16 + (lane >> 4) * 4 + q4;
        if (m < N) {
#pragma unroll
          for (int j = 0; j < FC; ++j) {
            const int n = n0 + wc + j * 16 + r15;
            Co[(size_t)m * ldC + n] = fmaxf(acc[i][j][q4] + biast[n], 0.0f);
          }
        }
      }
    }
  } else {
    ushort* Ct = (ushort*)SM;
#pragma unroll
    for (int i = 0; i < FR; ++i) {
#pragma unroll
      for (int q4 = 0; q4 < 4; ++q4) {
        const int row = wr + i * 16 + (lane >> 4) * 4 + q4;
#pragma unroll
        for (int j = 0; j < FC; ++j) {
          const int col = wc + j * 16 + r15;
          float v = acc[i][j][q4];
          v = (EPI == 0) ? tanhf(v + biast[n0 + col]) : fmaxf(v + biast[n0 + col], 0.0f);
          Ct[row * BN + col] = f2b(v);
        }
      }
    }
    __syncthreads();
    constexpr int C8 = BN / 8;
    constexpr int UNITS = BM * C8;
    ushort* Co = (ushort*)Cout;
#pragma unroll
    for (int u0 = 0; u0 < UNITS; u0 += 256) {
      const int u = u0 + tid;
      const int row = u / C8, c8 = u % C8;
      const int rl = m0 + row;
      if (rl < mcnt) {
        const int grow = ADAPT ? permt[rl] : rl;
        *(short8*)(Co + (size_t)grow * ldC + n0 + c8 * 8) =
            *(const short8*)(Ct + row * BN + c8 * 8);
      }
    }
  }
}

extern "C" void kernel_launch(void* const* d_in, const int* in_sizes, int n_in,
                              void* d_out, int out_size, void* d_ws, size_t ws_size,
                              hipStream_t stream) {
  const float* X       = (const float*)d_in[0];
  const int*   ntype   = (const int*)d_in[1];
  const int*   eidx    = (const int*)d_in[2];
  const int*   etype   = (const int*)d_in[3];
  const float* adapt_W = (const float*)d_in[5];
  const float* adapt_b = (const float*)d_in[6];
  const float* W_rel   = (const float*)d_in[7];
  const float* W_self  = (const float*)d_in[8];
  const float* b_self  = (const float*)d_in[9];

  const int N = in_sizes[1];
  const int E = in_sizes[3];
  const int* src = eidx;
  const int* dst = eidx + E;

  char* ws = (char*)d_ws;
  size_t o = 0;
  auto alloc = [&](size_t bytes) { void* p = ws + o; o += (bytes + 255) & ~255ull; return p; };

  ushort* S     = (ushort*)alloc((size_t)N * LDH * 2);  // 71.7 MB; also aliases Xb
  ushort* Xb    = S;                                     // Xb dead before S written
  ushort* h     = (ushort*)alloc((size_t)N * D * 2);
  ushort* Wab   = (ushort*)alloc((size_t)NTYPES * D * DIN * 2);
  ushort* Wcat2 = (ushort*)alloc((size_t)2 * D * LDH * 2);
  int*   deg    = (int*)alloc((size_t)N * 4);
  float* inv    = (float*)alloc((size_t)N * 4);
  int*   perm   = (int*)alloc((size_t)N * 4);
  int*   rowptr = (int*)alloc((size_t)(N + 1) * 4);
  int*   cursor = (int*)alloc((size_t)N * 4);
  int*   epack  = (int*)alloc((size_t)E * 4);
  int*   bsum   = (int*)alloc(1024 * 4);
  int*   blockcnt = (int*)alloc((size_t)1024 * NTYPES * 4);
  int*   boffset  = (int*)alloc((size_t)1024 * NTYPES * 4);
  int*   cnt    = (int*)alloc(NTYPES * 4);
  int*   offt   = (int*)alloc(NTYPES * 4);

  const int thr = 256;
  const int nbN = (N + thr - 1) / thr;
  const int nbE = (E + thr - 1) / thr;

  k_zero<<<nbN, thr, 0, stream>>>(deg, N);

  // bf16 conversions / weight packing
  k_cvt_bf16<<<(N * DIN / 4 + thr - 1) / thr, thr, 0, stream>>>(X, Xb, N * DIN / 4);
  k_cvt_bf16<<<(NTYPES * D * DIN / 4 + thr - 1) / thr, thr, 0, stream>>>(adapt_W, Wab,
                                                                          NTYPES * D * DIN / 4);
  dim3 gW2(D * LDH / 256, 2);
  k_pack_wcat2<<<gW2, 256, 0, stream>>>(W_rel, W_self, Wcat2);

  // type sort (ballot-based) + degrees
  k_type_blockcnt<<<nbN, thr, 0, stream>>>(ntype, blockcnt, N);
  k_type_scan<<<1, 64, 0, stream>>>(blockcnt, boffset, cnt, offt, nbN);
  k_type_scatter<<<nbN, thr, 0, stream>>>(ntype, boffset, perm, N);
  k_degree<<<nbE, thr, 0, stream>>>(dst, deg, E);

  // CSR by dst (scan_add also computes inv_deg)
  k_scan_block<<<nbN, 256, 0, stream>>>(deg, rowptr, bsum, N);
  k_scan_bsum<<<1, 64, 0, stream>>>(bsum, nbN);
  k_scan_add<<<nbN, 256, 0, stream>>>(rowptr, cursor, bsum, deg, inv, N, E);
  k_sortedges<<<nbE, 256, 0, stream>>>(src, dst, etype, cursor, epack, E);

  // adaptation: h = tanh(X @ W_t^T + b_t), bf16 — 64x64 tiles, 1D swizzled grid
  const int mtA = (N + 63) / 64;
  const int nwgA = NTYPES * mtA * (D / 64);
  k_mfma_gemm<64, 64, D / 64, DIN, true, 0, 6><<<nwgA, 256, 0, stream>>>(
      Xb, Wab, adapt_b, perm, cnt, offt, h, N, D);

  // two relational layers, aggregate-first:
  //   S = [inv*Σ_rel h[src] | h]  (bf16, N x 1792)
  //   h_next = relu(S @ Wcat2[l] + b)   (K=1792 GEMM, 64x64 TLP tiles)
  const int nwgL = mtA * (D / 64);   // 313 * 4
  for (int l = 0; l < 2; ++l) {
    k_aggregate<<<(N + 3) / 4, 256, 0, stream>>>(h, rowptr, epack, inv, S, N);
    const ushort* Wl = Wcat2 + (size_t)l * D * LDH;
    const float* bl = b_self + (size_t)l * D;
    if (l == 0)
      k_mfma_gemm<64, 64, D / 64, LDH, false, 1, 6><<<nwgL, 256, 0, stream>>>(
          S, Wl, bl, nullptr, nullptr, nullptr, h, N, D);
    else
      k_mfma_gemm<64, 64, D / 64, LDH, false, 2, 6><<<nwgL, 256, 0, stream>>>(
          S, Wl, bl, nullptr, nullptr, nullptr, d_out, N, D);
  }
}

// Round 11
// 214.121 us; speedup vs baseline: 1.9315x; 1.9315x over previous
//
#include <hip/hip_runtime.h>

constexpr int NTYPES = 8;
constexpr int NREL   = 6;
constexpr int NSLOT  = 7;          // 6 relations + self
constexpr int D      = 256;
constexpr int DIN    = 512;
constexpr int LDH    = NSLOT * D;  // 1792

using short8 = __attribute__((ext_vector_type(8))) short;
using f32x4  = __attribute__((ext_vector_type(4))) float;

__device__ __forceinline__ ushort f2b(float f) {  // f32 -> bf16 RNE
  unsigned u = __float_as_uint(f);
  u += 0x7fffu + ((u >> 16) & 1u);
  return (ushort)(u >> 16);
}
__device__ __forceinline__ float b2f(unsigned bits16) {
  return __uint_as_float(bits16 << 16);
}

#define GLOAD_LDS16(g, l)                                              \
  __builtin_amdgcn_global_load_lds(                                    \
      (__attribute__((address_space(1))) void*)(g),                    \
      (__attribute__((address_space(3))) void*)(l), 16, 0, 0)

// ---------------- fused prep: zero deg | cvt X | cvt adapt_W | pack Wcat ------
// one launch, grid partitioned by blockIdx (independent jobs co-schedule;
// round-10 lesson: 4 serial small launches cost more than their work).
__global__ void k_prep_fused(int* __restrict__ deg,
                             const float* __restrict__ X, ushort* __restrict__ Xb,
                             const float* __restrict__ Wa, ushort* __restrict__ Wab,
                             const float* __restrict__ Wrel, const float* __restrict__ Wself,
                             ushort* __restrict__ Wcat,
                             int N, int nz, int nx, int nw, int n4x, int n4w) {
  const int b = blockIdx.x;
  const int tid = threadIdx.x;
  if (b < nz) {
    int i = b * 256 + tid;
    if (i < N) deg[i] = 0;
  } else if (b < nz + nx) {
    int i = (b - nz) * 256 + tid;
    if (i < n4x) {
      float4 v = ((const float4*)X)[i];
      ushort4 o; o.x = f2b(v.x); o.y = f2b(v.y); o.z = f2b(v.z); o.w = f2b(v.w);
      ((ushort4*)Xb)[i] = o;
    }
  } else if (b < nz + nx + nw) {
    int i = (b - nz - nx) * 256 + tid;
    if (i < n4w) {
      float4 v = ((const float4*)Wa)[i];
      ushort4 o; o.x = f2b(v.x); o.y = f2b(v.y); o.z = f2b(v.z); o.w = f2b(v.w);
      ((ushort4*)Wab)[i] = o;
    }
  } else {
    int local = b - nz - nx - nw;        // 0 .. 2*7*256-1
    int l = local / (NSLOT * 256);
    int s = (local % (NSLOT * 256)) / 256;
    int o = (local % 256) * 256 + tid;   // over D*D
    int e = o >> 8, d = o & 255;
    float v = (s < NREL) ? Wrel[(((size_t)l * NREL + s) * D + d) * D + e]
                         : Wself[((size_t)l * D + d) * D + e];
    Wcat[(((size_t)l * NSLOT + s) * D + e) * D + d] = f2b(v);
  }
}

// ---- fused: per-block type histogram (ballot) | degree atomics ----
__global__ void k_count_fused(const int* __restrict__ ntype, int* __restrict__ blockcnt,
                              const int* __restrict__ dst, int* __restrict__ deg,
                              int N, int E, int nbN) {
  __shared__ int cnt[NTYPES];
  const int b = blockIdx.x;
  if (b < nbN) {
    int i = b * 256 + threadIdx.x;
    if (threadIdx.x < NTYPES) cnt[threadIdx.x] = 0;
    __syncthreads();
    int t = (i < N) ? ntype[i] : -1;
#pragma unroll
    for (int ty = 0; ty < NTYPES; ++ty) {
      unsigned long long m = __ballot(t == ty);
      if ((threadIdx.x & 63) == 0 && m) atomicAdd(&cnt[ty], __popcll(m));
    }
    __syncthreads();
    if (threadIdx.x < NTYPES) blockcnt[b * NTYPES + threadIdx.x] = cnt[threadIdx.x];
  } else {
    int e = (b - nbN) * 256 + threadIdx.x;
    if (e < E) atomicAdd(&deg[dst[e]], 1);
  }
}

__global__ void k_type_scan(const int* __restrict__ blockcnt, int* __restrict__ boffset,
                            int* __restrict__ cnt, int* __restrict__ offt, int nb) {
  __shared__ int tot[NTYPES];
  __shared__ int base[NTYPES];
  int t = threadIdx.x;
  if (t < NTYPES) {
    int s = 0;
    for (int b = 0; b < nb; ++b) {
      boffset[b * NTYPES + t] = s;
      s += blockcnt[b * NTYPES + t];
    }
    tot[t] = s;
    cnt[t] = s;
  }
  __syncthreads();
  if (t == 0) {
    int s = 0;
    for (int ty = 0; ty < NTYPES; ++ty) { base[ty] = s; offt[ty] = s; s += tot[ty]; }
  }
  __syncthreads();
  if (t < NTYPES)
    for (int b = 0; b < nb; ++b) boffset[b * NTYPES + t] += base[t];
}

// ---- fused: type scatter (perm) | degree block-scan (rowptr partials) ----
__global__ void k_scatter_scan(const int* __restrict__ ntype, const int* __restrict__ boffset,
                               int* __restrict__ perm,
                               const int* __restrict__ deg, int* __restrict__ rowptr,
                               int* __restrict__ bsum, int N, int nbN) {
  __shared__ int sm[256];
  const int b = blockIdx.x;
  if (b < nbN) {
    int i = b * 256 + threadIdx.x;
    if (threadIdx.x < NTYPES) sm[threadIdx.x] = boffset[b * NTYPES + threadIdx.x];
    __syncthreads();
    int t = (i < N) ? ntype[i] : -1;
    int lane = threadIdx.x & 63;
#pragma unroll
    for (int ty = 0; ty < NTYPES; ++ty) {
      unsigned long long m = __ballot(t == ty);
      if (m) {
        int wbase = 0;
        if (lane == 0) wbase = atomicAdd(&sm[ty], __popcll(m));
        wbase = __shfl(wbase, 0);
        if (t == ty) {
          int rank = __popcll(m & ((1ull << lane) - 1ull));
          perm[wbase + rank] = i;
        }
      }
    }
  } else {
    const int bb = b - nbN;
    int i = bb * 256 + threadIdx.x;
    int v = (i < N) ? deg[i] : 0;
    sm[threadIdx.x] = v;
    __syncthreads();
    for (int o = 1; o < 256; o <<= 1) {
      int t = (threadIdx.x >= o) ? sm[threadIdx.x - o] : 0;
      __syncthreads();
      sm[threadIdx.x] += t;
      __syncthreads();
    }
    if (i < N) rowptr[i] = sm[threadIdx.x] - v;   // exclusive within block
    if (threadIdx.x == 255) bsum[bb] = sm[255];
  }
}

__global__ void k_scan_bsum(int* bsum, int nb) {
  if (threadIdx.x == 0) {
    int s = 0;
    for (int b = 0; b < nb; ++b) { int t = bsum[b]; bsum[b] = s; s += t; }
  }
}
// adds block offsets AND computes inv_deg in the same pass
__global__ void k_scan_add(int* __restrict__ rowptr, int* __restrict__ cursor,
                           const int* __restrict__ bsum, const int* __restrict__ deg,
                           float* __restrict__ inv, int N, int E) {
  int i = blockIdx.x * 256 + threadIdx.x;
  if (i < N) {
    int r = rowptr[i] + bsum[blockIdx.x];
    rowptr[i] = r;
    cursor[i] = r;
    inv[i] = 1.0f / fmaxf((float)deg[i], 1.0f);
  }
  if (i == 0) rowptr[N] = E;
}
__global__ void k_sortedges(const int* __restrict__ src, const int* __restrict__ dst,
                            const int* __restrict__ et, int* cursor,
                            int* __restrict__ epack, int E) {
  int e = blockIdx.x * 256 + threadIdx.x;
  if (e < E) {
    int pos = atomicAdd(&cursor[dst[e]], 1);
    epack[pos] = (src[e] << 3) | et[e];
  }
}

// ---------------- MFMA GEMM (1D swizzled grid, LDS-staged epilogue) -------------
// C[m][n] = sum_k A[m][k] * B[n][k]   (B stored row-per-output-col, k-contiguous)
// BMxBN tile, 4 waves (2x2), BK=32, bf16 in / f32 acc / bf16 out.
// 1D grid, n-tile fastest, bijective XCD swizzle (T1/m204).
// K-loop barriers are REAL __syncthreads() (IR fence + vmcnt/lgkmcnt drain +
// s_barrier); raw s_barrier is IntrNoMem and let STAGE hoist (rounds 6-7 bugs).
template <int BM, int BN, int NTN, int KDIM, bool ADAPT, int OCC>
__global__ __launch_bounds__(256, OCC)
void k_mfma_gemm(const ushort* __restrict__ A, const ushort* __restrict__ B,
                 const float* __restrict__ bias,
                 const int* __restrict__ perm, const int* __restrict__ cnt,
                 const int* __restrict__ off,
                 ushort* __restrict__ Cout, int N, int ldC) {
  // bijective XCD swizzle (works for any nwg)
  const int nwg = gridDim.x;
  const int qq = nwg >> 3, rr = nwg & 7;
  const int xcd = blockIdx.x & 7, idx = blockIdx.x >> 3;
  const int wgid = (xcd < rr ? xcd * (qq + 1) : rr * (qq + 1) + (xcd - rr) * qq) + idx;

  int mcnt = N, mtile, ntile;
  const int* permt = nullptr;
  const ushort* Bt = B;
  const float* biast = bias;
  if (ADAPT) {
    const int mt = nwg / (NTYPES * NTN);
    const int t = wgid / (mt * NTN);
    const int rem = wgid % (mt * NTN);
    mtile = rem / NTN;
    ntile = rem % NTN;
    mcnt = cnt[t];
    permt = perm + off[t];
    Bt = B + (size_t)t * D * KDIM;
    biast = bias + t * D;
  } else {
    mtile = wgid / NTN;
    ntile = wgid % NTN;
  }
  const int m0 = mtile * BM;
  if (m0 >= mcnt) return;
  const int n0 = ntile * BN;

  __shared__ ushort SM[2][2][BM * 32];   // [buf][A=0/B=1][row*32+k]
  static_assert(BM * BN <= 2 * 2 * BM * 32, "C tile must fit in staging LDS");

  const int tid  = threadIdx.x;
  const int lane = tid & 63;
  const int w    = tid >> 6;
  constexpr int FR = BM / 32;
  constexpr int FC = BN / 32;
  const int wr   = (w >> 1) * (BM / 2);
  const int wc   = (w & 1) * (BN / 2);

  // staging: (BM/16) x 1KB calls per matrix; wave w does calls {w, w+4, ...}.
  // XOR swizzle on GLOBAL source slot (LDS dest linear), undone at ds_read.
  constexpr int PW = BM / 16 / 4;
  const ushort* gA[PW];
  const ushort* gB[PW];
  int lo[PW];
#pragma unroll
  for (int u = 0; u < PW; ++u) {
    const int c  = w + u * 4;
    const int r  = c * 16 + (lane >> 2);
    const int sl = (lane & 3) ^ ((r >> 1) & 3);
    int ga;
    if (ADAPT) ga = permt[min(m0 + r, mcnt - 1)];
    else       ga = min(m0 + r, N - 1);
    gA[u] = A + (size_t)ga * KDIM + sl * 8;
    gB[u] = Bt + (size_t)(n0 + r) * KDIM + sl * 8;
    lo[u] = c * 512;
  }

  auto STAGE = [&](int k0, int buf) {
#pragma unroll
    for (int u = 0; u < PW; ++u) {
      GLOAD_LDS16(gA[u] + k0, &SM[buf][0][lo[u]]);
      GLOAD_LDS16(gB[u] + k0, &SM[buf][1][lo[u]]);
    }
  };

  f32x4 acc[FR][FC] = {};
  const int r15 = lane & 15;
  const int g   = lane >> 4;
  const int gsw = g ^ ((r15 >> 1) & 3);

  STAGE(0, 0);
  __syncthreads();

  constexpr int NT = KDIM / 32;
  int curb = 0;
#pragma unroll
  for (int kt = 0; kt < NT; ++kt) {
    if (kt + 1 < NT) STAGE((kt + 1) * 32, curb ^ 1);   // prefetch next tile

    short8 af[FR], bf[FC];
#pragma unroll
    for (int i = 0; i < FR; ++i)
      af[i] = *(const short8*)(&SM[curb][0][(wr + i * 16 + r15) * 32 + gsw * 8]);
#pragma unroll
    for (int j = 0; j < FC; ++j)
      bf[j] = *(const short8*)(&SM[curb][1][(wc + j * 16 + r15) * 32 + gsw * 8]);
#pragma unroll
    for (int i = 0; i < FR; ++i)
#pragma unroll
      for (int j = 0; j < FC; ++j)
        acc[i][j] = __builtin_amdgcn_mfma_f32_16x16x32_bf16(af[i], bf[j], acc[i][j], 0, 0, 0);

    __syncthreads();   // real fence+barrier: prefetch landed, reads joined
    curb ^= 1;
  }

  // ---- epilogue: C/D layout (m89): col = lane&15, row = (lane>>4)*4 + reg ----
  ushort* Ct = (ushort*)SM;
#pragma unroll
  for (int i = 0; i < FR; ++i) {
#pragma unroll
    for (int q4 = 0; q4 < 4; ++q4) {
      const int row = wr + i * 16 + (lane >> 4) * 4 + q4;
#pragma unroll
      for (int j = 0; j < FC; ++j) {
        const int col = wc + j * 16 + r15;
        float v = acc[i][j][q4];
        if (ADAPT) v = tanhf(v + biast[n0 + col]);
        Ct[row * BN + col] = f2b(v);
      }
    }
  }
  __syncthreads();
  constexpr int C8 = BN / 8;
  constexpr int UNITS = BM * C8;
#pragma unroll
  for (int u0 = 0; u0 < UNITS; u0 += 256) {
    const int u = u0 + tid;
    const int row = u / C8, c8 = u % C8;
    const int rl = m0 + row;
    if (rl < mcnt) {
      const int grow = ADAPT ? permt[rl] : rl;
      *(short8*)(Cout + (size_t)grow * ldC + n0 + c8 * 8) =
          *(const short8*)(Ct + row * BN + c8 * 8);
    }
  }
}

// ---------------- CSR gather-combine ----------------
// out[v] = relu( (sum_{e in in(v)} Hall[src_e][rel_e*256 + :]) * inv[v]
//                + Hall[v][6*256 + :] + bias )
// one wave per node, lane owns 4 channels; edge loop 8-wide unrolled so 8
// independent L2/L3 gathers are in flight per wave.
template <bool LAST>
__global__ void k_combine(const ushort* __restrict__ Hall, const int* __restrict__ rowptr,
                          const int* __restrict__ epack, const float* __restrict__ invd,
                          const float* __restrict__ bias, void* __restrict__ outp, int N) {
  int v = blockIdx.x * 4 + (threadIdx.x >> 6);
  if (v >= N) return;
  int lane = threadIdx.x & 63;
  int e0 = rowptr[v], e1 = rowptr[v + 1];
  const uint2 s = *(const uint2*)(Hall + (size_t)v * LDH + NREL * D + lane * 4);
  float iv = invd[v];
  const float4 b4 = *(const float4*)(bias + lane * 4);

  float a0 = 0.f, a1 = 0.f, a2 = 0.f, a3 = 0.f;
  int e = e0;
  for (; e + 8 <= e1; e += 8) {
    uint2 u[8];
#pragma unroll
    for (int k = 0; k < 8; ++k) {
      int p = epack[e + k];
      u[k] = *(const uint2*)(Hall + (size_t)(p >> 3) * LDH + (p & 7) * D + lane * 4);
    }
#pragma unroll
    for (int k = 0; k < 8; ++k) {
      a0 += b2f(u[k].x & 0xffffu);
      a1 += __uint_as_float(u[k].x & 0xffff0000u);
      a2 += b2f(u[k].y & 0xffffu);
      a3 += __uint_as_float(u[k].y & 0xffff0000u);
    }
  }
  if (e + 4 <= e1) {
    uint2 u[4];
#pragma unroll
    for (int k = 0; k < 4; ++k) {
      int p = epack[e + k];
      u[k] = *(const uint2*)(Hall + (size_t)(p >> 3) * LDH + (p & 7) * D + lane * 4);
    }
#pragma unroll
    for (int k = 0; k < 4; ++k) {
      a0 += b2f(u[k].x & 0xffffu);
      a1 += __uint_as_float(u[k].x & 0xffff0000u);
      a2 += b2f(u[k].y & 0xffffu);
      a3 += __uint_as_float(u[k].y & 0xffff0000u);
    }
    e += 4;
  }
  for (; e < e1; ++e) {
    int p = epack[e];
    const uint2 u = *(const uint2*)(Hall + (size_t)(p >> 3) * LDH + (p & 7) * D + lane * 4);
    a0 += b2f(u.x & 0xffffu);
    a1 += __uint_as_float(u.x & 0xffff0000u);
    a2 += b2f(u.y & 0xffffu);
    a3 += __uint_as_float(u.y & 0xffff0000u);
  }
  float o0 = fmaxf(fmaf(a0, iv, b2f(s.x & 0xffffu)) + b4.x, 0.f);
  float o1 = fmaxf(fmaf(a1, iv, __uint_as_float(s.x & 0xffff0000u)) + b4.y, 0.f);
  float o2 = fmaxf(fmaf(a2, iv, b2f(s.y & 0xffffu)) + b4.z, 0.f);
  float o3 = fmaxf(fmaf(a3, iv, __uint_as_float(s.y & 0xffff0000u)) + b4.w, 0.f);
  if (LAST) {
    float4 o; o.x = o0; o.y = o1; o.z = o2; o.w = o3;
    ((float4*)outp)[(size_t)v * 64 + lane] = o;
  } else {
    ushort4 o; o.x = f2b(o0); o.y = f2b(o1); o.z = f2b(o2); o.w = f2b(o3);
    ((ushort4*)outp)[(size_t)v * 64 + lane] = o;
  }
}

extern "C" void kernel_launch(void* const* d_in, const int* in_sizes, int n_in,
                              void* d_out, int out_size, void* d_ws, size_t ws_size,
                              hipStream_t stream) {
  const float* X       = (const float*)d_in[0];
  const int*   ntype   = (const int*)d_in[1];
  const int*   eidx    = (const int*)d_in[2];
  const int*   etype   = (const int*)d_in[3];
  const float* adapt_W = (const float*)d_in[5];
  const float* adapt_b = (const float*)d_in[6];
  const float* W_rel   = (const float*)d_in[7];
  const float* W_self  = (const float*)d_in[8];
  const float* b_self  = (const float*)d_in[9];

  const int N = in_sizes[1];
  const int E = in_sizes[3];
  const int* src = eidx;
  const int* dst = eidx + E;

  char* ws = (char*)d_ws;
  size_t o = 0;
  auto alloc = [&](size_t bytes) { void* p = ws + o; o += (bytes + 255) & ~255ull; return p; };

  ushort* Hall  = (ushort*)alloc((size_t)N * LDH * 2);  // 71.7 MB; also aliases Xb
  ushort* Xb    = Hall;                                  // Xb dead before Hall written
  ushort* h     = (ushort*)alloc((size_t)N * D * 2);
  ushort* Wab   = (ushort*)alloc((size_t)NTYPES * D * DIN * 2);
  ushort* Wcat  = (ushort*)alloc((size_t)2 * NSLOT * D * D * 2);
  int*   deg    = (int*)alloc((size_t)N * 4);
  float* inv    = (float*)alloc((size_t)N * 4);
  int*   perm   = (int*)alloc((size_t)N * 4);
  int*   rowptr = (int*)alloc((size_t)(N + 1) * 4);
  int*   cursor = (int*)alloc((size_t)N * 4);
  int*   epack  = (int*)alloc((size_t)E * 4);
  int*   bsum   = (int*)alloc(1024 * 4);
  int*   blockcnt = (int*)alloc((size_t)1024 * NTYPES * 4);
  int*   boffset  = (int*)alloc((size_t)1024 * NTYPES * 4);
  int*   cnt    = (int*)alloc(NTYPES * 4);
  int*   offt   = (int*)alloc(NTYPES * 4);

  const int thr = 256;
  const int nbN = (N + thr - 1) / thr;
  const int nbE = (E + thr - 1) / thr;

  // fused prep: zero deg | X->bf16 | adapt_W->bf16 | pack Wcat  (1 launch)
  const int n4x = N * DIN / 4;
  const int n4w = NTYPES * D * DIN / 4;
  const int nz = nbN;
  const int nx = (n4x + thr - 1) / thr;
  const int nw = (n4w + thr - 1) / thr;
  const int np = 2 * NSLOT * (D * D / 256);
  k_prep_fused<<<nz + nx + nw + np, thr, 0, stream>>>(deg, X, Xb, adapt_W, Wab,
                                                      W_rel, W_self, Wcat,
                                                      N, nz, nx, nw, n4x, n4w);

  // fused: type histogram | degree atomics  (1 launch)
  k_count_fused<<<nbN + nbE, thr, 0, stream>>>(ntype, blockcnt, dst, deg, N, E, nbN);
  k_type_scan<<<1, 64, 0, stream>>>(blockcnt, boffset, cnt, offt, nbN);
  // fused: type scatter | degree block-scan  (1 launch)
  k_scatter_scan<<<2 * nbN, thr, 0, stream>>>(ntype, boffset, perm, deg, rowptr, bsum, N, nbN);
  k_scan_bsum<<<1, 64, 0, stream>>>(bsum, nbN);
  k_scan_add<<<nbN, 256, 0, stream>>>(rowptr, cursor, bsum, deg, inv, N, E);
  k_sortedges<<<nbE, 256, 0, stream>>>(src, dst, etype, cursor, epack, E);

  // adaptation: h = tanh(X @ W_t^T + b_t), bf16 — 64x64 tiles, 1D swizzled grid
  const int mtA = (N + 63) / 64;
  const int nwgA = NTYPES * mtA * (D / 64);
  k_mfma_gemm<64, 64, D / 64, DIN, true, 6><<<nwgA, 256, 0, stream>>>(
      Xb, Wab, adapt_b, perm, cnt, offt, h, N, D);

  // two relational layers — 128x128 tiles, n-fast 1D grid + XCD swizzle
  const int mtL = (N + 127) / 128;
  const int nwgL = mtL * (LDH / 128);
  for (int l = 0; l < 2; ++l) {
    const ushort* Wl = Wcat + (size_t)l * NSLOT * D * D;
    k_mfma_gemm<128, 128, LDH / 128, D, false, 4><<<nwgL, 256, 0, stream>>>(
        h, Wl, nullptr, nullptr, nullptr, nullptr, Hall, N, LDH);
    if (l == 0)
      k_combine<false><<<(N + 3) / 4, 256, 0, stream>>>(Hall, rowptr, epack, inv,
                                                        b_self + (size_t)l * D, h, N);
    else
      k_combine<true><<<(N + 3) / 4, 256, 0, stream>>>(Hall, rowptr, epack, inv,
                                                       b_self + (size_t)l * D, d_out, N);
  }
}